// Round 20
// baseline (80.526 us; speedup 1.0000x reference)
//
#include <hip/hip_runtime.h>

typedef float f4 __attribute__((ext_vector_type(4)));
typedef float f2 __attribute__((ext_vector_type(2)));

#define LL 64
#define BB 2048
#define DD 512
#define GB 2                 // batches per block (consecutive)
#define NBLK (BB / GB)       // 1024 blocks
#define XD 4                 // x prefetch depth (32KB/CU in flight)
#define WD 3                 // weight prefetch depth (R16's validated optimum)
#define LOG2E 1.442695040888963f

__device__ __forceinline__ float fexp2(float v){ return __builtin_amdgcn_exp2f(v); }
__device__ __forceinline__ float frcp_(float v){ return __builtin_amdgcn_rcpf(v); }
__device__ __forceinline__ float fsigm(float z){ return frcp_(1.0f + fexp2(-LOG2E*z)); }
__device__ __forceinline__ float ftanh_(float z){ return 1.0f - 2.0f*frcp_(1.0f + fexp2(2.0f*LOG2E*z)); }

__device__ __forceinline__ f4 ld4(const float* __restrict__ p){ return *(const f4*)p; }
__device__ __forceinline__ f4 vexp2(f4 v){ f4 r; r[0]=fexp2(v[0]); r[1]=fexp2(v[1]); r[2]=fexp2(v[2]); r[3]=fexp2(v[3]); return r; }
__device__ __forceinline__ f4 vrcp(f4 v){ f4 r; r[0]=frcp_(v[0]); r[1]=frcp_(v[1]); r[2]=frcp_(v[2]); r[3]=frcp_(v[3]); return r; }

// Quad reduction via DPP quad_perm adds: pure VALU, no DS pipe (R12: -8.4%)
__device__ __forceinline__ float quad_reduce_dpp(float v){
  int t1 = __builtin_amdgcn_update_dpp(0, __builtin_bit_cast(int, v),
                                       0xB1 /*quad_perm [1,0,3,2]*/, 0xF, 0xF, true);
  v += __builtin_bit_cast(float, t1);
  int t2 = __builtin_amdgcn_update_dpp(0, __builtin_bit_cast(int, v),
                                       0x4E /*quad_perm [2,3,0,1]*/, 0xF, 0xF, true);
  v += __builtin_bit_cast(float, t2);
  return v;
}

// (128,3): ~168 VGPR cap. XD=4/WD=3 footprint ~156 -> fits without spill.
__global__ __launch_bounds__(128, 3) void rnn_fused_kernel(
    const float* __restrict__ x,
    const float* __restrict__ wxp, const float* __restrict__ wgp,
    const float* __restrict__ whp, const float* __restrict__ wup,
    const float* __restrict__ mp,  const float* __restrict__ fcw,
    const float* __restrict__ fcb, float* __restrict__ out)
{
  __shared__ float part[GB][LL][33];   // [g][l][quad-group], +1 pad
  const int tid = threadIdx.x;
  const int b0  = blockIdx.x;
  const int d0  = tid << 2;
  const int grp = tid >> 2;

  const f4 fw = ld4(fcw + d0);
  const f2 fwlo = __builtin_shufflevector(fw, fw, 0, 1);
  const f2 fwhi = __builtin_shufflevector(fw, fw, 2, 3);
  const size_t PL = (size_t)BB * DD;

  const float* xbase[GB];
  #pragma unroll
  for (int g = 0; g < GB; ++g)
    xbase[g] = x + (size_t)(b0 * GB + g) * DD + d0;

  // ---- prefetch rings: x[1..XD] (HBM cover), weights[1..WD] (L2-hot)
  f4 xq[GB][XD];
  f4 wxq[WD], wgq[WD], whq[WD], wuq[WD], mmq[WD];
  #pragma unroll
  for (int k = 0; k < XD; ++k){
    #pragma unroll
    for (int g = 0; g < GB; ++g)
      xq[g][k] = ld4(xbase[g] + (size_t)(1 + k) * PL);
  }
  #pragma unroll
  for (int k = 0; k < WD; ++k){
    const int s = 1 + k;
    wxq[k] = ld4(wxp + s * DD + d0);
    wgq[k] = ld4(wgp + s * DD + d0);
    whq[k] = ld4(whp + s * DD + d0);
    wuq[k] = ld4(wup + s * DD + d0);
    mmq[k] = ld4(mp  + s * DD + d0);
  }

  // ---- t = 0
  f4 w0x = ld4(wxp + d0);
  f4 w0g = ld4(wgp + d0);
  f4 h0v[GB], h[GB], xb[GB];
  #pragma unroll
  for (int g = 0; g < GB; ++g){
    f4 x0 = ld4(xbase[g]);
    float c0 = quad_reduce_dpp(x0[0]*fw[0] + x0[1]*fw[1] + x0[2]*fw[2] + x0[3]*fw[3]);
    if ((tid & 3) == 0) part[g][0][grp] = c0;

    float c1 = 0.0f;
    #pragma unroll
    for (int j = 0; j < 4; ++j){
      h0v[g][j] = ftanh_(x0[j] * w0x[j]);
      xb[g][j]  = h0v[g][j] * w0g[j] + x0[j];
      c1       += xb[g][j] * fw[j];
    }
    h[g] = h0v[g];
    c1 = quad_reduce_dpp(c1);
    if ((tid & 3) == 0) part[g][1][grp] = c1;
  }

  // ---- main scan: t = 1..62; unroll 12 = lcm(XD,WD) -> both rotations renamed
  #pragma unroll 3
  for (int t = 1; t < LL - 1; ++t){
    const int xpn = (t + XD <= LL - 2) ? (t + XD) : (LL - 2);
    const int wpn = (t + WD <= LL - 2) ? (t + WD) : (LL - 2);
    f4 xC[GB];
    #pragma unroll
    for (int g = 0; g < GB; ++g)
      xC[g] = ld4(xbase[g] + (size_t)xpn * PL);
    f4 wxn = ld4(wxp + wpn * DD + d0);
    f4 wgn = ld4(wgp + wpn * DD + d0);
    f4 whn = ld4(whp + wpn * DD + d0);
    f4 wun = ld4(wup + wpn * DD + d0);
    f4 mmn = ld4(mp  + wpn * DD + d0);

    // consume ring fronts
    f4 wxs = wxq[0] * (2.0f * LOG2E);
    f4 whs = whq[0] * (-LOG2E);
    f4 wus = wuq[0] * (-LOG2E);
    f4 wgc = wgq[0];
    f4 mmc = mmq[0];

    #pragma unroll
    for (int g = 0; g < GB; ++g){
      f4 xtr  = xb[g] + mmc * (xq[g][0] - xb[g]);
      f4 u    = 1.0f - 2.0f * vrcp(1.0f + vexp2(xtr * wxs));
      f4 sarg = h[g] * whs + u * wus;
      f4 ff   = vrcp(1.0f + vexp2(sarg)) * mmc;
      f4 mn   = __builtin_elementwise_min(1.0f - ff, u);
      f4 hn   = ff * h[g] + mn;
      hn      = __builtin_elementwise_max(hn, h0v[g]);
      h[g]  = hn;
      xb[g] = hn * wgc + xtr;

      f2 c2 = __builtin_shufflevector(xb[g], xb[g], 0, 1) * fwlo
            + __builtin_shufflevector(xb[g], xb[g], 2, 3) * fwhi;
      float cc = quad_reduce_dpp(c2[0] + c2[1]);
      if ((tid & 3) == 0) part[g][t + 1][grp] = cc;

      #pragma unroll
      for (int k = 0; k < XD - 1; ++k) xq[g][k] = xq[g][k + 1];
      xq[g][XD - 1] = xC[g];
    }

    #pragma unroll
    for (int k = 0; k < WD - 1; ++k){
      wxq[k] = wxq[k + 1]; wgq[k] = wgq[k + 1]; whq[k] = whq[k + 1];
      wuq[k] = wuq[k + 1]; mmq[k] = mmq[k + 1];
    }
    wxq[WD - 1] = wxn; wgq[WD - 1] = wgn; whq[WD - 1] = whn;
    wuq[WD - 1] = wun; mmq[WD - 1] = mmn;
  }

  __syncthreads();

  // ---- epilogue: 128 threads = 2 batches x 64 l-rows
  {
    const int l = tid & 63;
    const int g = tid >> 6;
    float s = 0.0f;
    #pragma unroll
    for (int j = 0; j < 32; ++j) s += part[g][l][j];
    out[(size_t)l * BB + (b0 * GB + g)] = fsigm(s + fcb[0]);
  }
}

extern "C" void kernel_launch(void* const* d_in, const int* in_sizes, int n_in,
                              void* d_out, int out_size, void* d_ws, size_t ws_size,
                              hipStream_t stream)
{
  const float* x   = (const float*)d_in[0];
  const float* wx  = (const float*)d_in[1];
  const float* wg  = (const float*)d_in[2];
  const float* wh  = (const float*)d_in[3];
  const float* wu  = (const float*)d_in[4];
  const float* m   = (const float*)d_in[5];
  const float* fcw = (const float*)d_in[6];
  const float* fcb = (const float*)d_in[7];
  float* out = (float*)d_out;
  rnn_fused_kernel<<<dim3(NBLK), dim3(128), 0, stream>>>(x, wx, wg, wh, wu, m, fcw, fcb, out);
}

// Round 21
// 50.831 us; speedup vs baseline: 1.5842x; 1.5842x over previous
//
#include <hip/hip_runtime.h>

typedef float f4 __attribute__((ext_vector_type(4)));
typedef float f2 __attribute__((ext_vector_type(2)));

#define LL 64
#define BB 2048
#define DD 512
#define GB 2                 // batches per block (consecutive)
#define NBLK (BB / GB)       // 1024 blocks
#define DEPTH 3              // prefetch depth (R16 optimum: covers latency, no spill)
#define LOG2E 1.442695040888963f

__device__ __forceinline__ float fexp2(float v){ return __builtin_amdgcn_exp2f(v); }
__device__ __forceinline__ float frcp_(float v){ return __builtin_amdgcn_rcpf(v); }
__device__ __forceinline__ float fsigm(float z){ return frcp_(1.0f + fexp2(-LOG2E*z)); }
__device__ __forceinline__ float ftanh_(float z){ return 1.0f - 2.0f*frcp_(1.0f + fexp2(2.0f*LOG2E*z)); }

__device__ __forceinline__ f4 ld4(const float* __restrict__ p){ return *(const f4*)p; }
__device__ __forceinline__ f4 vexp2(f4 v){ f4 r; r[0]=fexp2(v[0]); r[1]=fexp2(v[1]); r[2]=fexp2(v[2]); r[3]=fexp2(v[3]); return r; }
__device__ __forceinline__ f4 vrcp(f4 v){ f4 r; r[0]=frcp_(v[0]); r[1]=frcp_(v[1]); r[2]=frcp_(v[2]); r[3]=frcp_(v[3]); return r; }

// Quad reduction via DPP quad_perm adds: pure VALU, no DS pipe (R12: -8.4%)
__device__ __forceinline__ float quad_reduce_dpp(float v){
  int t1 = __builtin_amdgcn_update_dpp(0, __builtin_bit_cast(int, v),
                                       0xB1 /*quad_perm [1,0,3,2]*/, 0xF, 0xF, true);
  v += __builtin_bit_cast(float, t1);
  int t2 = __builtin_amdgcn_update_dpp(0, __builtin_bit_cast(int, v),
                                       0x4E /*quad_perm [2,3,0,1]*/, 0xF, 0xF, true);
  v += __builtin_bit_cast(float, t2);
  return v;
}

// (128,3): cap VGPR at ~170. DEPTH=3 footprint ~145 -> fits WITHOUT spill.
// R16-validated optimum: 51.1 us. Every perturbation tested (depth 1/2/4/8,
// GB 1/4, 4 waves/SIMD, f2, nt, LDS staging, split XD/WD) regresses.
__global__ __launch_bounds__(128, 3) void rnn_fused_kernel(
    const float* __restrict__ x,
    const float* __restrict__ wxp, const float* __restrict__ wgp,
    const float* __restrict__ whp, const float* __restrict__ wup,
    const float* __restrict__ mp,  const float* __restrict__ fcw,
    const float* __restrict__ fcb, float* __restrict__ out)
{
  __shared__ float part[GB][LL][33];   // [g][l][quad-group], +1 pad
  const int tid = threadIdx.x;
  const int b0  = blockIdx.x;
  const int d0  = tid << 2;
  const int grp = tid >> 2;

  const f4 fw = ld4(fcw + d0);
  const f2 fwlo = __builtin_shufflevector(fw, fw, 0, 1);
  const f2 fwhi = __builtin_shufflevector(fw, fw, 2, 3);
  const size_t PL = (size_t)BB * DD;

  // consecutive batches: block handles b = b0*GB .. b0*GB+GB-1
  const float* xbase[GB];
  #pragma unroll
  for (int g = 0; g < GB; ++g)
    xbase[g] = x + (size_t)(b0 * GB + g) * DD + d0;

  // ---- deep prefetch rings: x[1..DEPTH] and weights[1..DEPTH]
  f4 xq[GB][DEPTH];
  f4 wxq[DEPTH], wgq[DEPTH], whq[DEPTH], wuq[DEPTH], mmq[DEPTH];
  #pragma unroll
  for (int k = 0; k < DEPTH; ++k){
    const int s = 1 + k;
    #pragma unroll
    for (int g = 0; g < GB; ++g)
      xq[g][k] = ld4(xbase[g] + (size_t)s * PL);
    wxq[k] = ld4(wxp + s * DD + d0);
    wgq[k] = ld4(wgp + s * DD + d0);
    whq[k] = ld4(whp + s * DD + d0);
    wuq[k] = ld4(wup + s * DD + d0);
    mmq[k] = ld4(mp  + s * DD + d0);
  }

  // ---- t = 0
  f4 w0x = ld4(wxp + d0);
  f4 w0g = ld4(wgp + d0);
  f4 h0v[GB], h[GB], xb[GB];
  #pragma unroll
  for (int g = 0; g < GB; ++g){
    f4 x0 = ld4(xbase[g]);
    float c0 = quad_reduce_dpp(x0[0]*fw[0] + x0[1]*fw[1] + x0[2]*fw[2] + x0[3]*fw[3]);
    if ((tid & 3) == 0) part[g][0][grp] = c0;

    float c1 = 0.0f;
    #pragma unroll
    for (int j = 0; j < 4; ++j){
      h0v[g][j] = ftanh_(x0[j] * w0x[j]);
      xb[g][j]  = h0v[g][j] * w0g[j] + x0[j];
      c1       += xb[g][j] * fw[j];
    }
    h[g] = h0v[g];
    c1 = quad_reduce_dpp(c1);
    if ((tid & 3) == 0) part[g][1][grp] = c1;
  }

  // ---- main scan: t = 1..62 (x[63]/w[63] never used); unroll 3 -> ring
  //      rotation becomes register renaming
  #pragma unroll 3
  for (int t = 1; t < LL - 1; ++t){
    const int tpn = (t + DEPTH <= LL - 2) ? (t + DEPTH) : (LL - 2);
    // issue ALL next-step loads first (consumed DEPTH iters from now)
    f4 xC[GB];
    #pragma unroll
    for (int g = 0; g < GB; ++g)
      xC[g] = ld4(xbase[g] + (size_t)tpn * PL);
    f4 wxn = ld4(wxp + tpn * DD + d0);
    f4 wgn = ld4(wgp + tpn * DD + d0);
    f4 whn = ld4(whp + tpn * DD + d0);
    f4 wun = ld4(wup + tpn * DD + d0);
    f4 mmn = ld4(mp  + tpn * DD + d0);

    // consume ring fronts (loaded DEPTH iters ago)
    f4 wxs = wxq[0] * (2.0f * LOG2E);
    f4 whs = whq[0] * (-LOG2E);
    f4 wus = wuq[0] * (-LOG2E);
    f4 wgc = wgq[0];
    f4 mmc = mmq[0];

    #pragma unroll
    for (int g = 0; g < GB; ++g){
      f4 xtr  = xb[g] + mmc * (xq[g][0] - xb[g]);
      f4 u    = 1.0f - 2.0f * vrcp(1.0f + vexp2(xtr * wxs));
      f4 sarg = h[g] * whs + u * wus;
      f4 ff   = vrcp(1.0f + vexp2(sarg)) * mmc;
      f4 mn   = __builtin_elementwise_min(1.0f - ff, u);
      f4 hn   = ff * h[g] + mn;
      hn      = __builtin_elementwise_max(hn, h0v[g]);
      h[g]  = hn;
      xb[g] = hn * wgc + xtr;

      f2 c2 = __builtin_shufflevector(xb[g], xb[g], 0, 1) * fwlo
            + __builtin_shufflevector(xb[g], xb[g], 2, 3) * fwhi;
      float cc = quad_reduce_dpp(c2[0] + c2[1]);
      if ((tid & 3) == 0) part[g][t + 1][grp] = cc;

      #pragma unroll
      for (int k = 0; k < DEPTH - 1; ++k) xq[g][k] = xq[g][k + 1];
      xq[g][DEPTH - 1] = xC[g];
    }

    #pragma unroll
    for (int k = 0; k < DEPTH - 1; ++k){
      wxq[k] = wxq[k + 1]; wgq[k] = wgq[k + 1]; whq[k] = whq[k + 1];
      wuq[k] = wuq[k + 1]; mmq[k] = mmq[k + 1];
    }
    wxq[DEPTH - 1] = wxn; wgq[DEPTH - 1] = wgn; whq[DEPTH - 1] = whn;
    wuq[DEPTH - 1] = wun; mmq[DEPTH - 1] = mmn;
  }

  __syncthreads();

  // ---- epilogue: 128 threads = 2 batches x 64 l-rows
  {
    const int l = tid & 63;
    const int g = tid >> 6;
    float s = 0.0f;
    #pragma unroll
    for (int j = 0; j < 32; ++j) s += part[g][l][j];
    out[(size_t)l * BB + (b0 * GB + g)] = fsigm(s + fcb[0]);
  }
}

extern "C" void kernel_launch(void* const* d_in, const int* in_sizes, int n_in,
                              void* d_out, int out_size, void* d_ws, size_t ws_size,
                              hipStream_t stream)
{
  const float* x   = (const float*)d_in[0];
  const float* wx  = (const float*)d_in[1];
  const float* wg  = (const float*)d_in[2];
  const float* wh  = (const float*)d_in[3];
  const float* wu  = (const float*)d_in[4];
  const float* m   = (const float*)d_in[5];
  const float* fcw = (const float*)d_in[6];
  const float* fcb = (const float*)d_in[7];
  float* out = (float*)d_out;
  rnn_fused_kernel<<<dim3(NBLK), dim3(128), 0, stream>>>(x, wx, wg, wh, wu, m, fcw, fcb, out);
}